// Round 1
// baseline (416.400 us; speedup 1.0000x reference)
//
#include <hip/hip_runtime.h>
#include <stdint.h>

typedef unsigned short u16;
typedef __attribute__((ext_vector_type(8))) short short8;
typedef __attribute__((ext_vector_type(4))) float f32x4;

#define MFMA16 __builtin_amdgcn_mfma_f32_16x16x32_bf16

#define GLOAD_LDS16(gsrc, ldst) \
  __builtin_amdgcn_global_load_lds((const __attribute__((address_space(1))) void*)(gsrc), \
                                   (__attribute__((address_space(3))) void*)(ldst), 16, 0, 0)

__device__ __forceinline__ u16 f2bf(float x) {
  union { float f; uint32_t u; } v; v.f = x;
  uint32_t r = v.u + 0x7FFFu + ((v.u >> 16) & 1u);
  return (u16)(r >> 16);
}
__device__ __forceinline__ float bf2f(u16 b) {
  union { uint32_t u; float f; } v; v.u = ((uint32_t)b) << 16;
  return v.f;
}

// ---------------- convert f32 -> bf16 (elementwise, vectorized) ----------------
__global__ __launch_bounds__(256) void convert_bf16_kernel(
    const float* __restrict__ in, u16* __restrict__ out, int n) {
  int i = (blockIdx.x * 256 + threadIdx.x) * 8;
  if (i >= n) return;
  float4 a = *(const float4*)(in + i);
  float4 b = *(const float4*)(in + i + 4);
  short8 t;
  t[0] = (short)f2bf(a.x); t[1] = (short)f2bf(a.y);
  t[2] = (short)f2bf(a.z); t[3] = (short)f2bf(a.w);
  t[4] = (short)f2bf(b.x); t[5] = (short)f2bf(b.y);
  t[6] = (short)f2bf(b.z); t[7] = (short)f2bf(b.w);
  *(short8*)(out + i) = t;
}

// ---------------- transpose f32 [K][N] -> bf16 [N][K] (64x64 tiles) ----------------
__global__ __launch_bounds__(256) void transpose_w64(
    const float* __restrict__ W, u16* __restrict__ WT, int KK, int NN) {
  __shared__ float tile[64][68];
  const int t = threadIdx.x;
  const int k0 = blockIdx.x * 64, n0 = blockIdx.y * 64;
  {
    int r = t >> 2, c0 = (t & 3) * 16;
    const float* src = W + (size_t)(k0 + r) * NN + n0 + c0;
#pragma unroll
    for (int j = 0; j < 16; j += 4) {
      float4 v = *(const float4*)(src + j);
      tile[r][c0 + j + 0] = v.x; tile[r][c0 + j + 1] = v.y;
      tile[r][c0 + j + 2] = v.z; tile[r][c0 + j + 3] = v.w;
    }
  }
  __syncthreads();
  {
    int n = t >> 2, kq = (t & 3) * 16;
    short8 t0, t1;
#pragma unroll
    for (int j = 0; j < 8; ++j)  t0[j] = (short)f2bf(tile[kq + j][n]);
#pragma unroll
    for (int j = 0; j < 8; ++j)  t1[j] = (short)f2bf(tile[kq + 8 + j][n]);
    u16* dst = WT + (size_t)(n0 + n) * KK + k0 + kq;
    *(short8*)dst = t0;
    *(short8*)(dst + 8) = t1;
  }
}

// ---------------- transpose V bf16 [b*2048+s][h*64+c] -> VT [(b*16+h)*64+c][s] ----------------
__global__ __launch_bounds__(256) void transpose_v64(
    const u16* __restrict__ vin, u16* __restrict__ vout) {
  __shared__ u16 tile[64][80];
  const int t = threadIdx.x;
  const int s0 = blockIdx.x * 64;
  const int bh = blockIdx.y;  // b*16+h
  const int b = bh >> 4, h = bh & 15;
  {
    int r = t >> 2, c0 = (t & 3) * 16;
    const u16* src = vin + (size_t)(b * 2048 + s0 + r) * 1024 + h * 64 + c0;
    *(short8*)&tile[r][c0] = *(const short8*)src;
    *(short8*)&tile[r][c0 + 8] = *(const short8*)(src + 8);
  }
  __syncthreads();
  {
    int c = t >> 2, s4 = (t & 3) * 16;
    short8 t0, t1;
#pragma unroll
    for (int j = 0; j < 8; ++j) t0[j] = (short)tile[s4 + j][c];
#pragma unroll
    for (int j = 0; j < 8; ++j) t1[j] = (short)tile[s4 + 8 + j][c];
    u16* dst = vout + (size_t)(bh * 64 + c) * 2048 + s0 + s4;
    *(short8*)dst = t0;
    *(short8*)(dst + 8) = t1;
  }
}

// ---------------- GEMM: D[r][n] = sum_k A[r][k]*BT[n][k], m97-style 128x128/BK=64 ----------------
// mode -1: z = blockIdx.z selects weight (0=q scale, 1=k, 2=v, 3=g sigmoid+bg), bf16 out
// mode  4: final, f32 out + bo
__global__ __launch_bounds__(256) void gemm_bt128(
    const u16* __restrict__ A, const u16* __restrict__ BTbase,
    void* __restrict__ dstbase, const float* __restrict__ bvec, int mode) {
  const int K = 1024;
  const int tid = threadIdx.x, lane = tid & 63, w = tid >> 6;
  const int wr = w >> 1, wc = w & 1;
  const int l15 = lane & 15, lg = lane >> 4;
  const int z = (mode < 0) ? (int)blockIdx.z : mode;
  const u16* BT = (mode < 0) ? BTbase + (size_t)z * 1024 * 1024 : BTbase;
  const int rbase = blockIdx.x * 128;
  const int nbase = blockIdx.y * 128;
  __shared__ u16 lsA[128 * 64];
  __shared__ u16 lsB[128 * 64];
  f32x4 acc[4][4] = {};
  const int col8 = (lane & 7) * 8;
  for (int kt = 0; kt < K / 64; ++kt) {
#pragma unroll
    for (int i = 0; i < 4; ++i) {
      int row = w * 32 + i * 8 + (lane >> 3);
      const u16* sa = A + (size_t)(rbase + row) * K + kt * 64 + col8;
      GLOAD_LDS16(sa, lsA + (w * 32 + i * 8) * 64 + lane * 8);
      const u16* sb = BT + (size_t)(nbase + row) * K + kt * 64 + col8;
      GLOAD_LDS16(sb, lsB + (w * 32 + i * 8) * 64 + lane * 8);
    }
    __syncthreads();
#pragma unroll
    for (int kk = 0; kk < 2; ++kk) {
      short8 af[4], bfr[4];
#pragma unroll
      for (int m = 0; m < 4; ++m)
        af[m] = *(const short8*)&lsA[(wr * 64 + m * 16 + l15) * 64 + kk * 32 + lg * 8];
#pragma unroll
      for (int n = 0; n < 4; ++n)
        bfr[n] = *(const short8*)&lsB[(wc * 64 + n * 16 + l15) * 64 + kk * 32 + lg * 8];
#pragma unroll
      for (int m = 0; m < 4; ++m)
#pragma unroll
        for (int n = 0; n < 4; ++n)
          acc[m][n] = MFMA16(af[m], bfr[n], acc[m][n], 0, 0, 0);
    }
    __syncthreads();
  }
  const int r0 = rbase + wr * 64;
  const int c0 = nbase + wc * 64;
  if (z == 4) {
    float* out = (float*)dstbase;
#pragma unroll
    for (int m = 0; m < 4; ++m)
#pragma unroll
      for (int n = 0; n < 4; ++n)
#pragma unroll
        for (int i = 0; i < 4; ++i) {
          int r = r0 + m * 16 + lg * 4 + i;
          int c = c0 + n * 16 + l15;
          out[(size_t)r * 1024 + c] = acc[m][n][i] + bvec[c];
        }
  } else {
    u16* dq = (u16*)dstbase + (size_t)z * 4096 * 1024;
#pragma unroll
    for (int m = 0; m < 4; ++m)
#pragma unroll
      for (int n = 0; n < 4; ++n)
#pragma unroll
        for (int i = 0; i < 4; ++i) {
          int r = r0 + m * 16 + lg * 4 + i;
          int c = c0 + n * 16 + l15;
          float v = acc[m][n][i];
          if (z == 0) v *= 0.125f;                                   // q / sqrt(64)
          else if (z == 3) v = 1.f / (1.f + __expf(-(v + bvec[c]))); // sigmoid gate
          dq[(size_t)r * 1024 + c] = f2bf(v);
        }
  }
}

// ---------------- flash attention with pair bias + mask + gate ----------------
// grid (32 q-tiles, 16 heads), 4 waves: wave w owns q rows qt*64+w*16..+15, loops both batches
__global__ __launch_bounds__(256) void attn_kernel(
    const u16* __restrict__ qws, const u16* __restrict__ kws,
    const u16* __restrict__ vt, const u16* __restrict__ gws,
    const float* __restrict__ bias, const float* __restrict__ mask,
    u16* __restrict__ og) {
  const int tid = threadIdx.x;
  const int lane = tid & 63;
  const int w = tid >> 6;
  const int qt = blockIdx.x;
  const int h = blockIdx.y;
  const int l15 = lane & 15;
  const int lg = lane >> 4;
  const int qb = qt * 64 + w * 16;
  __shared__ u16 plds[4][16][72];  // per-wave P tile, padded stride (conflict-free-ish)

  short8 qf[2][2];
#pragma unroll
  for (int b = 0; b < 2; ++b)
#pragma unroll
    for (int hh = 0; hh < 2; ++hh)
      qf[b][hh] = *(const short8*)(qws + (size_t)(b * 2048 + qb + l15) * 1024 +
                                   h * 64 + hh * 32 + lg * 8);

  f32x4 O[2][4] = {};
  float mrow[2][4], lrow[2][4];
#pragma unroll
  for (int b = 0; b < 2; ++b)
#pragma unroll
    for (int i = 0; i < 4; ++i) { mrow[b][i] = -3e38f; lrow[b][i] = 0.f; }

  for (int kb = 0; kb < 32; ++kb) {
    const int k0 = kb * 64;
    // bias fragments: shared across batches, read once
    float bv[4][4];
#pragma unroll
    for (int ks = 0; ks < 4; ++ks) {
      const float* bp = bias + ((size_t)h * 2048 + qb + lg * 4) * 2048 + k0 + ks * 16 + l15;
#pragma unroll
      for (int i = 0; i < 4; ++i) bv[ks][i] = bp[(size_t)i * 2048];
    }
#pragma unroll
    for (int b = 0; b < 2; ++b) {
      f32x4 s[4];
#pragma unroll
      for (int ks = 0; ks < 4; ++ks) {
        const u16* kp = kws + (size_t)(b * 2048 + k0 + ks * 16 + l15) * 1024 + h * 64 + lg * 8;
        short8 kf0 = *(const short8*)(kp);
        short8 kf1 = *(const short8*)(kp + 32);
        f32x4 z = {0.f, 0.f, 0.f, 0.f};
        s[ks] = MFMA16(qf[b][0], kf0, z, 0, 0, 0);
        s[ks] = MFMA16(qf[b][1], kf1, s[ks], 0, 0, 0);
      }
#pragma unroll
      for (int ks = 0; ks < 4; ++ks) {
        float mk = (mask[b * 2048 + k0 + ks * 16 + l15] - 1.0f) * 1e9f;
#pragma unroll
        for (int i = 0; i < 4; ++i) s[ks][i] += bv[ks][i] + mk;
      }
      // online softmax, rows live on 16-lane groups
#pragma unroll
      for (int i = 0; i < 4; ++i) {
        float t = fmaxf(fmaxf(s[0][i], s[1][i]), fmaxf(s[2][i], s[3][i]));
        t = fmaxf(t, __shfl_xor(t, 1));
        t = fmaxf(t, __shfl_xor(t, 2));
        t = fmaxf(t, __shfl_xor(t, 4));
        t = fmaxf(t, __shfl_xor(t, 8));
        float nm = fmaxf(mrow[b][i], t);
        float sc = __expf(mrow[b][i] - nm);
        mrow[b][i] = nm;
        float rs = 0.f;
#pragma unroll
        for (int ks = 0; ks < 4; ++ks) {
          float p = __expf(s[ks][i] - nm);
          s[ks][i] = p;
          rs += p;
        }
        rs += __shfl_xor(rs, 1); rs += __shfl_xor(rs, 2);
        rs += __shfl_xor(rs, 4); rs += __shfl_xor(rs, 8);
        lrow[b][i] = lrow[b][i] * sc + rs;
#pragma unroll
        for (int cf = 0; cf < 4; ++cf) O[b][cf][i] *= sc;
      }
      // P -> LDS (reshape to A-fragment layout); same-wave, no barrier needed
#pragma unroll
      for (int ks = 0; ks < 4; ++ks)
#pragma unroll
        for (int i = 0; i < 4; ++i)
          plds[w][lg * 4 + i][ks * 16 + l15] = f2bf(s[ks][i]);
      // PV
#pragma unroll
      for (int ks2 = 0; ks2 < 2; ++ks2) {
        short8 pa = *(const short8*)&plds[w][l15][ks2 * 32 + lg * 8];
#pragma unroll
        for (int cf = 0; cf < 4; ++cf) {
          short8 vf = *(const short8*)(vt + (size_t)((b * 16 + h) * 64 + cf * 16 + l15) * 2048 +
                                       k0 + ks2 * 32 + lg * 8);
          O[b][cf] = MFMA16(pa, vf, O[b][cf], 0, 0, 0);
        }
      }
    }
  }
  // epilogue: 1/l, gate, store bf16
#pragma unroll
  for (int b = 0; b < 2; ++b)
#pragma unroll
    for (int cf = 0; cf < 4; ++cf)
#pragma unroll
      for (int i = 0; i < 4; ++i) {
        int q = qb + lg * 4 + i;
        size_t idx = (size_t)(b * 2048 + q) * 1024 + h * 64 + cf * 16 + l15;
        float val = O[b][cf][i] / lrow[b][i];
        float g = bf2f(gws[idx]);
        og[idx] = f2bf(val * g);
      }
}

extern "C" void kernel_launch(void* const* d_in, const int* in_sizes, int n_in,
                              void* d_out, int out_size, void* d_ws, size_t ws_size,
                              hipStream_t stream) {
  const float* x    = (const float*)d_in[0];
  const float* mask = (const float*)d_in[1];
  const float* bias = (const float*)d_in[2];
  const float* wq   = (const float*)d_in[3];
  const float* wk   = (const float*)d_in[4];
  const float* wv   = (const float*)d_in[5];
  const float* wg   = (const float*)d_in[6];
  const float* bg   = (const float*)d_in[7];
  const float* wo   = (const float*)d_in[8];
  const float* bo   = (const float*)d_in[9];
  float* out = (float*)d_out;

  char* ws = (char*)d_ws;
  const size_t MB = 1ull << 20;
  u16* xb   = (u16*)(ws + 0);        // 4096x1024 bf16 input          (8 MB)
  u16* wt   = (u16*)(ws + 8 * MB);   // 4x WT [1024][1024] bf16       (8 MB)
  u16* wot  = (u16*)(ws + 16 * MB);  // WOT [1024][1024] bf16         (2 MB)
  u16* proj = (u16*)(ws + 18 * MB);  // q,k,v,g each 4096x1024 bf16   (32 MB)
  u16* vtp  = (u16*)(ws + 50 * MB);  // VT [b,h,c,s] bf16             (8 MB)
  u16* og   = (u16*)(ws + 58 * MB);  // gated attention out bf16      (8 MB)
  const size_t PSZ = (size_t)4096 * 1024;

  convert_bf16_kernel<<<2048, 256, 0, stream>>>(x, xb, 4096 * 1024);

  dim3 tg(16, 16);
  transpose_w64<<<tg, 256, 0, stream>>>(wq, wt + 0 * 1048576, 1024, 1024);
  transpose_w64<<<tg, 256, 0, stream>>>(wk, wt + 1 * 1048576, 1024, 1024);
  transpose_w64<<<tg, 256, 0, stream>>>(wv, wt + 2 * 1048576, 1024, 1024);
  transpose_w64<<<tg, 256, 0, stream>>>(wg, wt + 3 * 1048576, 1024, 1024);
  transpose_w64<<<tg, 256, 0, stream>>>(wo, wot, 1024, 1024);

  gemm_bt128<<<dim3(32, 8, 4), 256, 0, stream>>>(xb, wt, (void*)proj, bg, -1);

  transpose_v64<<<dim3(32, 32), 256, 0, stream>>>(proj + 2 * PSZ, vtp);

  attn_kernel<<<dim3(32, 16), 256, 0, stream>>>(proj, proj + PSZ, vtp, proj + 3 * PSZ,
                                                bias, mask, og);

  gemm_bt128<<<dim3(32, 8, 1), 256, 0, stream>>>(og, wot, (void*)out, bo, 4);
}